// Round 2
// baseline (792.619 us; speedup 1.0000x reference)
//
#include <hip/hip_runtime.h>

// Scaling-and-squaring velocity exponentiation, circular bounds, fp32.
// v (2,128,128,128,3). 8 ping-pong passes. This version: 4 x-consecutive
// voxels per thread -> center load/store become 3x dwordx4, 4 independent
// gather chains per thread for MLP (round-1 showed latency-bound: 2.2 TB/s
// HBM, 21% VALU, minimal traffic).

#define NVOX (2 * 128 * 128 * 128)
#define NGRP (NVOX / 4)

__global__ __launch_bounds__(256) void sq_step4(
    const float* __restrict__ vin, float* __restrict__ vout,
    float scale, int add_grid)
{
    int tid = blockIdx.x * 256 + threadIdx.x;        // group id < NGRP
    int x0 = (tid & 31) << 2;                        // 32 groups of 4 along x
    int y  = (tid >> 5) & 127;
    int z  = (tid >> 12) & 127;
    int bb = (tid >> 19) << 21;                      // b * D*H*W

    // center: 48 contiguous bytes, 16B-aligned -> 3 x float4
    const float4* vin4 = (const float4*)(vin + (size_t)tid * 12);
    float4 c0 = vin4[0], c1 = vin4[1], c2 = vin4[2];
    float v[12] = { c0.x, c0.y, c0.z, c0.w,
                    c1.x, c1.y, c1.z, c1.w,
                    c2.x, c2.y, c2.z, c2.w };
    float o[12];

#pragma unroll
    for (int i = 0; i < 4; ++i) {
        float vz = v[3 * i + 0] * scale;
        float vy = v[3 * i + 1] * scale;
        float vx = v[3 * i + 2] * scale;
        int   x  = x0 + i;

        float pz = (float)z + vz, py = (float)y + vy, px = (float)x + vx;
        float fz = floorf(pz), fy = floorf(py), fx = floorf(px);
        float wz1 = pz - fz, wy1 = py - fy, wx1 = px - fx;
        float wz0 = 1.0f - wz1, wy0 = 1.0f - wy1, wx0 = 1.0f - wx1;

        int iz0 = ((int)fz) & 127, iy0 = ((int)fy) & 127, ix0 = ((int)fx) & 127;
        int iz1 = (iz0 + 1) & 127, iy1 = (iy0 + 1) & 127, ix1 = (ix0 + 1) & 127;

        float wzy00 = wz0 * wy0, wzy01 = wz0 * wy1;
        float wzy10 = wz1 * wy0, wzy11 = wz1 * wy1;

        float oz = vz, oy = vy, ox = vx;

#define CORNER(IZ, IY, IX, WW)                                              \
        {                                                                   \
            size_t lin = (size_t)(bb + ((IZ) << 14) + ((IY) << 7) + (IX)) * 3; \
            float w = (WW);                                                 \
            oz += w * (vin[lin + 0] * scale);                               \
            oy += w * (vin[lin + 1] * scale);                               \
            ox += w * (vin[lin + 2] * scale);                               \
        }
        CORNER(iz0, iy0, ix0, wzy00 * wx0)
        CORNER(iz0, iy0, ix1, wzy00 * wx1)
        CORNER(iz0, iy1, ix0, wzy01 * wx0)
        CORNER(iz0, iy1, ix1, wzy01 * wx1)
        CORNER(iz1, iy0, ix0, wzy10 * wx0)
        CORNER(iz1, iy0, ix1, wzy10 * wx1)
        CORNER(iz1, iy1, ix0, wzy11 * wx0)
        CORNER(iz1, iy1, ix1, wzy11 * wx1)
#undef CORNER

        if (add_grid) { oz += (float)z; oy += (float)y; ox += (float)x; }
        o[3 * i + 0] = oz;
        o[3 * i + 1] = oy;
        o[3 * i + 2] = ox;
    }

    float4* vout4 = (float4*)(vout + (size_t)tid * 12);
    vout4[0] = make_float4(o[0], o[1], o[2],  o[3]);
    vout4[1] = make_float4(o[4], o[5], o[6],  o[7]);
    vout4[2] = make_float4(o[8], o[9], o[10], o[11]);
}

extern "C" void kernel_launch(void* const* d_in, const int* in_sizes, int n_in,
                              void* d_out, int out_size, void* d_ws, size_t ws_size,
                              hipStream_t stream) {
    const float* vel = (const float*)d_in[0];
    float* out = (float*)d_out;
    float* ws  = (float*)d_ws;    // one field: 50.3 MB

    dim3 grid(NGRP / 256), block(256);
    const float s = 1.0f / 256.0f;   // 1 / 2^STEPS

    sq_step4<<<grid, block, 0, stream>>>(vel, ws, s, 0);
    sq_step4<<<grid, block, 0, stream>>>(ws, out, 1.0f, 0);
    sq_step4<<<grid, block, 0, stream>>>(out, ws, 1.0f, 0);
    sq_step4<<<grid, block, 0, stream>>>(ws, out, 1.0f, 0);
    sq_step4<<<grid, block, 0, stream>>>(out, ws, 1.0f, 0);
    sq_step4<<<grid, block, 0, stream>>>(ws, out, 1.0f, 0);
    sq_step4<<<grid, block, 0, stream>>>(out, ws, 1.0f, 0);
    sq_step4<<<grid, block, 0, stream>>>(ws, out, 1.0f, 1);
}

// Round 3
// 635.442 us; speedup vs baseline: 1.2473x; 1.2473x over previous
//
#include <hip/hip_runtime.h>

// Scaling-and-squaring velocity exponentiation, circular bounds, fp32.
// v (2,128,128,128,3). 8 ping-pong passes.
// R1 (AoS, 1 vox/thread): 366us, transaction-bound (~430 lines/wave).
// R2 (AoS, 4 vox/thread): 792us REGRESSION - stride-48 float4 => 1.6x write amp.
// R3 (this): SoA component planes. Center loads/stores perfectly coalesced
// (4 lines/wave-instr), gathers span ~300B/instr (~5-6 lines). Step1 fuses
// AoS->SoA + /256; step8 fuses SoA->AoS + grid epilogue.

#define NVOX (2 * 128 * 128 * 128)

template <bool IN_AOS, bool OUT_AOS>
__global__ __launch_bounds__(256) void sq_step(
    const float* __restrict__ vin, float* __restrict__ vout, float scale)
{
    int tid = blockIdx.x * 256 + threadIdx.x;       // < NVOX
    int x = tid & 127;
    int y = (tid >> 7) & 127;
    int z = (tid >> 14) & 127;
    int bb = tid & ~((1 << 21) - 1);                // b * D*H*W

    const float* Vz = vin;
    const float* Vy = vin + NVOX;
    const float* Vx = vin + 2 * NVOX;

    float vz, vy, vx;
    if (IN_AOS) {
        size_t b3 = (size_t)tid * 3;
        vz = vin[b3 + 0]; vy = vin[b3 + 1]; vx = vin[b3 + 2];
    } else {
        vz = Vz[tid]; vy = Vy[tid]; vx = Vx[tid];
    }
    vz *= scale; vy *= scale; vx *= scale;

    float pz = (float)z + vz, py = (float)y + vy, px = (float)x + vx;
    float fz = floorf(pz), fy = floorf(py), fx = floorf(px);
    float wz1 = pz - fz, wy1 = py - fy, wx1 = px - fx;
    float wz0 = 1.0f - wz1, wy0 = 1.0f - wy1, wx0 = 1.0f - wx1;

    int iz0 = ((int)fz) & 127, iy0 = ((int)fy) & 127, ix0 = ((int)fx) & 127;
    int iz1 = (iz0 + 1) & 127, iy1 = (iy0 + 1) & 127, ix1 = (ix0 + 1) & 127;

    int zo0 = bb + (iz0 << 14), zo1 = bb + (iz1 << 14);
    int yo0 = iy0 << 7, yo1 = iy1 << 7;

    int lin[8];
    lin[0] = zo0 + yo0 + ix0;  lin[1] = zo0 + yo0 + ix1;
    lin[2] = zo0 + yo1 + ix0;  lin[3] = zo0 + yo1 + ix1;
    lin[4] = zo1 + yo0 + ix0;  lin[5] = zo1 + yo0 + ix1;
    lin[6] = zo1 + yo1 + ix0;  lin[7] = zo1 + yo1 + ix1;

    float w[8];
    {
        float wzy00 = wz0 * wy0, wzy01 = wz0 * wy1;
        float wzy10 = wz1 * wy0, wzy11 = wz1 * wy1;
        w[0] = wzy00 * wx0;  w[1] = wzy00 * wx1;
        w[2] = wzy01 * wx0;  w[3] = wzy01 * wx1;
        w[4] = wzy10 * wx0;  w[5] = wzy10 * wx1;
        w[6] = wzy11 * wx0;  w[7] = wzy11 * wx1;
    }

    // Batch-issue all 24 gather loads, then accumulate.
    float gz[8], gy[8], gx[8];
#pragma unroll
    for (int c = 0; c < 8; ++c) {
        if (IN_AOS) {
            size_t a = (size_t)lin[c] * 3;
            gz[c] = vin[a + 0]; gy[c] = vin[a + 1]; gx[c] = vin[a + 2];
        } else {
            gz[c] = Vz[lin[c]]; gy[c] = Vy[lin[c]]; gx[c] = Vx[lin[c]];
        }
    }

    float az = 0.f, ay = 0.f, ax = 0.f;
#pragma unroll
    for (int c = 0; c < 8; ++c) {
        az += w[c] * gz[c];
        ay += w[c] * gy[c];
        ax += w[c] * gx[c];
    }
    float oz = vz + az * scale;
    float oy = vy + ay * scale;
    float ox = vx + ax * scale;

    if (OUT_AOS) {   // final step: convert back + grid epilogue
        size_t b3 = (size_t)tid * 3;
        vout[b3 + 0] = oz + (float)z;
        vout[b3 + 1] = oy + (float)y;
        vout[b3 + 2] = ox + (float)x;
    } else {
        vout[tid]            = oz;
        vout[NVOX + tid]     = oy;
        vout[2 * NVOX + tid] = ox;
    }
}

extern "C" void kernel_launch(void* const* d_in, const int* in_sizes, int n_in,
                              void* d_out, int out_size, void* d_ws, size_t ws_size,
                              hipStream_t stream) {
    const float* vel = (const float*)d_in[0];
    float* out = (float*)d_out;   // SoA intermediate for even steps, AoS final
    float* ws  = (float*)d_ws;    // one SoA field: 50.3 MB

    dim3 grid(NVOX / 256), block(256);
    const float s = 1.0f / 256.0f;   // 1 / 2^STEPS

    sq_step<true,  false><<<grid, block, 0, stream>>>(vel, ws,  s);     // 1: AoS->SoA
    sq_step<false, false><<<grid, block, 0, stream>>>(ws,  out, 1.0f);  // 2
    sq_step<false, false><<<grid, block, 0, stream>>>(out, ws,  1.0f);  // 3
    sq_step<false, false><<<grid, block, 0, stream>>>(ws,  out, 1.0f);  // 4
    sq_step<false, false><<<grid, block, 0, stream>>>(out, ws,  1.0f);  // 5
    sq_step<false, false><<<grid, block, 0, stream>>>(ws,  out, 1.0f);  // 6
    sq_step<false, false><<<grid, block, 0, stream>>>(out, ws,  1.0f);  // 7
    sq_step<false, true ><<<grid, block, 0, stream>>>(ws,  out, 1.0f);  // 8: SoA->AoS+grid
}

// Round 4
// 442.978 us; speedup vs baseline: 1.7893x; 1.4345x over previous
//
#include <hip/hip_runtime.h>

// Scaling-and-squaring velocity exponentiation, circular bounds, fp32.
// v (2,128,128,128,3). 8 ping-pong passes.
// R1 (AoS, 1 vox/thr):        366us. latency-bound, 2.2TB/s, traffic ideal.
// R2 (AoS, 4 vox/thr along x): 792us. stride-48 float4 -> 1.6x write amp.
// R3 (SoA, 1 vox/thr):        635us. 3x VMEM instrs (no dwordx3 merge).
// R4 (this): AoS, 2 vox/thr along BATCH: identical per-stream pattern to R1
// (dwordx3 merges preserved), 2 independent gather chains -> 2x MLP.

#define DHW  (128 * 128 * 128)       // 2,097,152
#define NVOX (2 * DHW)

__global__ __launch_bounds__(256) void sq_step(
    const float* __restrict__ vin, float* __restrict__ vout,
    float scale, int add_grid)
{
    int tid = blockIdx.x * 256 + threadIdx.x;       // < DHW; handles b=0 and b=1
    int x = tid & 127;
    int y = (tid >> 7) & 127;
    int z = (tid >> 14) & 127;

    // center loads: consecutive 12B per lane, stride-12 across wave (merges to dwordx3)
    size_t base0 = (size_t)tid * 3;
    size_t base1 = (size_t)(tid + DHW) * 3;
    float vz0 = vin[base0 + 0], vy0 = vin[base0 + 1], vx0 = vin[base0 + 2];
    float vz1 = vin[base1 + 0], vy1 = vin[base1 + 1], vx1 = vin[base1 + 2];
    vz0 *= scale; vy0 *= scale; vx0 *= scale;
    vz1 *= scale; vy1 *= scale; vx1 *= scale;

    float fzc = (float)z, fyc = (float)y, fxc = (float)x;

    // ---- per-batch setup (independent chains) ----
    float oz0 = vz0, oy0 = vy0, ox0 = vx0;
    float oz1 = vz1, oy1 = vy1, ox1 = vx1;

#define SETUP(S, BB)                                                          \
    float pz##S = fzc + vz##S, py##S = fyc + vy##S, px##S = fxc + vx##S;      \
    float fz##S = floorf(pz##S), fy##S = floorf(py##S), fx##S = floorf(px##S);\
    float wz1##S = pz##S - fz##S, wy1##S = py##S - fy##S, wx1##S = px##S - fx##S; \
    float wz0##S = 1.0f - wz1##S, wy0##S = 1.0f - wy1##S, wx0##S = 1.0f - wx1##S; \
    int iz0##S = ((int)fz##S) & 127, iy0##S = ((int)fy##S) & 127, ix0##S = ((int)fx##S) & 127; \
    int iz1##S = (iz0##S + 1) & 127, iy1##S = (iy0##S + 1) & 127, ix1##S = (ix0##S + 1) & 127; \
    int zo0##S = (BB) + (iz0##S << 14), zo1##S = (BB) + (iz1##S << 14);       \
    int yo0##S = iy0##S << 7, yo1##S = iy1##S << 7;

    SETUP(0, 0)
    SETUP(1, DHW)
#undef SETUP

#define CORNER(S, ZO, YO, IX, WW)                                             \
    {                                                                         \
        size_t lin = (size_t)((ZO) + (YO) + (IX)) * 3;                        \
        float w = (WW);                                                       \
        oz##S += w * (vin[lin + 0] * scale);                                  \
        oy##S += w * (vin[lin + 1] * scale);                                  \
        ox##S += w * (vin[lin + 2] * scale);                                  \
    }

#define GATHER8(S)                                                            \
    {                                                                         \
        float wzy00 = wz0##S * wy0##S, wzy01 = wz0##S * wy1##S;               \
        float wzy10 = wz1##S * wy0##S, wzy11 = wz1##S * wy1##S;               \
        CORNER(S, zo0##S, yo0##S, ix0##S, wzy00 * wx0##S)                     \
        CORNER(S, zo0##S, yo0##S, ix1##S, wzy00 * wx1##S)                     \
        CORNER(S, zo0##S, yo1##S, ix0##S, wzy01 * wx0##S)                     \
        CORNER(S, zo0##S, yo1##S, ix1##S, wzy01 * wx1##S)                     \
        CORNER(S, zo1##S, yo0##S, ix0##S, wzy10 * wx0##S)                     \
        CORNER(S, zo1##S, yo0##S, ix1##S, wzy10 * wx1##S)                     \
        CORNER(S, zo1##S, yo1##S, ix0##S, wzy11 * wx0##S)                     \
        CORNER(S, zo1##S, yo1##S, ix1##S, wzy11 * wx1##S)                     \
    }

    GATHER8(0)
    GATHER8(1)
#undef GATHER8
#undef CORNER

    if (add_grid) {
        oz0 += fzc; oy0 += fyc; ox0 += fxc;
        oz1 += fzc; oy1 += fyc; ox1 += fxc;
    }

    vout[base0 + 0] = oz0; vout[base0 + 1] = oy0; vout[base0 + 2] = ox0;
    vout[base1 + 0] = oz1; vout[base1 + 1] = oy1; vout[base1 + 2] = ox1;
}

extern "C" void kernel_launch(void* const* d_in, const int* in_sizes, int n_in,
                              void* d_out, int out_size, void* d_ws, size_t ws_size,
                              hipStream_t stream) {
    const float* vel = (const float*)d_in[0];
    float* out = (float*)d_out;
    float* ws  = (float*)d_ws;    // one field: 50.3 MB

    dim3 grid(DHW / 256), block(256);
    const float s = 1.0f / 256.0f;   // 1 / 2^STEPS

    sq_step<<<grid, block, 0, stream>>>(vel, ws,  s,    0);
    sq_step<<<grid, block, 0, stream>>>(ws,  out, 1.0f, 0);
    sq_step<<<grid, block, 0, stream>>>(out, ws,  1.0f, 0);
    sq_step<<<grid, block, 0, stream>>>(ws,  out, 1.0f, 0);
    sq_step<<<grid, block, 0, stream>>>(out, ws,  1.0f, 0);
    sq_step<<<grid, block, 0, stream>>>(ws,  out, 1.0f, 0);
    sq_step<<<grid, block, 0, stream>>>(out, ws,  1.0f, 0);
    sq_step<<<grid, block, 0, stream>>>(ws,  out, 1.0f, 1);
}

// Round 5
// 357.138 us; speedup vs baseline: 2.2194x; 1.2404x over previous
//
#include <hip/hip_runtime.h>

// Scaling-and-squaring velocity exponentiation, circular bounds, fp32.
// v (2,128,128,128,3). 8 ping-pong passes.
// R1 (AoS, 1 vox/thr, 128x2 blocks): 366us. gather-path bound, 2.2TB/s.
// R2 (AoS, 4 vox/thr along x):       792us. stride-48 -> write amp.
// R3 (SoA):                          635us. 3x VMEM instrs.
// R4 (AoS, 2 vox/thr batch-split):   443us. MLP doesn't help; wave count does.
// R5 (this): R1 per-thread code, block = 64x4x4 brick (1024 thr). Gather
// footprint 66x6x6 ~= 28KB fits L1; y/z corner rows shared within block.

#define DHW  (128 * 128 * 128)
#define NVOX (2 * DHW)

__global__ __launch_bounds__(1024) void sq_step(
    const float* __restrict__ vin, float* __restrict__ vout,
    float scale, int add_grid)
{
    int t = threadIdx.x;
    int b = blockIdx.x;
    // block brick: 64 (x) x 4 (y) x 4 (z)
    int x = ((b & 1) << 6) | (t & 63);
    int y = (((b >> 1) & 31) << 2) | ((t >> 6) & 3);
    int z = (((b >> 6) & 31) << 2) | (t >> 8);
    int bb = (b >> 11) << 21;                       // batch * DHW

    int tid = bb + (z << 14) + (y << 7) + x;
    size_t base = (size_t)tid * 3;
    float vz = vin[base + 0] * scale;
    float vy = vin[base + 1] * scale;
    float vx = vin[base + 2] * scale;

    float pz = (float)z + vz, py = (float)y + vy, px = (float)x + vx;
    float fz = floorf(pz), fy = floorf(py), fx = floorf(px);
    float wz1 = pz - fz, wy1 = py - fy, wx1 = px - fx;
    float wz0 = 1.0f - wz1, wy0 = 1.0f - wy1, wx0 = 1.0f - wx1;

    int iz0 = ((int)fz) & 127, iy0 = ((int)fy) & 127, ix0 = ((int)fx) & 127;
    int iz1 = (iz0 + 1) & 127, iy1 = (iy0 + 1) & 127, ix1 = (ix0 + 1) & 127;

    int zo0 = bb + (iz0 << 14), zo1 = bb + (iz1 << 14);
    int yo0 = iy0 << 7, yo1 = iy1 << 7;

    float wzy00 = wz0 * wy0, wzy01 = wz0 * wy1;
    float wzy10 = wz1 * wy0, wzy11 = wz1 * wy1;

    float oz = vz, oy = vy, ox = vx;

#define CORNER(ZO, YO, IX, WW)                                          \
    {                                                                   \
        size_t lin = (size_t)((ZO) + (YO) + (IX)) * 3;                  \
        float w = (WW);                                                 \
        oz += w * (vin[lin + 0] * scale);                               \
        oy += w * (vin[lin + 1] * scale);                               \
        ox += w * (vin[lin + 2] * scale);                               \
    }
    CORNER(zo0, yo0, ix0, wzy00 * wx0)
    CORNER(zo0, yo0, ix1, wzy00 * wx1)
    CORNER(zo0, yo1, ix0, wzy01 * wx0)
    CORNER(zo0, yo1, ix1, wzy01 * wx1)
    CORNER(zo1, yo0, ix0, wzy10 * wx0)
    CORNER(zo1, yo0, ix1, wzy10 * wx1)
    CORNER(zo1, yo1, ix0, wzy11 * wx0)
    CORNER(zo1, yo1, ix1, wzy11 * wx1)
#undef CORNER

    if (add_grid) { oz += (float)z; oy += (float)y; ox += (float)x; }

    vout[base + 0] = oz;
    vout[base + 1] = oy;
    vout[base + 2] = ox;
}

extern "C" void kernel_launch(void* const* d_in, const int* in_sizes, int n_in,
                              void* d_out, int out_size, void* d_ws, size_t ws_size,
                              hipStream_t stream) {
    const float* vel = (const float*)d_in[0];
    float* out = (float*)d_out;
    float* ws  = (float*)d_ws;    // one field: 50.3 MB

    dim3 grid(NVOX / 1024), block(1024);
    const float s = 1.0f / 256.0f;   // 1 / 2^STEPS

    sq_step<<<grid, block, 0, stream>>>(vel, ws,  s,    0);
    sq_step<<<grid, block, 0, stream>>>(ws,  out, 1.0f, 0);
    sq_step<<<grid, block, 0, stream>>>(out, ws,  1.0f, 0);
    sq_step<<<grid, block, 0, stream>>>(ws,  out, 1.0f, 0);
    sq_step<<<grid, block, 0, stream>>>(out, ws,  1.0f, 0);
    sq_step<<<grid, block, 0, stream>>>(ws,  out, 1.0f, 0);
    sq_step<<<grid, block, 0, stream>>>(out, ws,  1.0f, 0);
    sq_step<<<grid, block, 0, stream>>>(ws,  out, 1.0f, 1);
}